// Round 6
// baseline (415.971 us; speedup 1.0000x reference)
//
#include <hip/hip_runtime.h>
#include <cstddef>

#define H 128
#define W 128
#define P_THRESH 20
#define LROWS 10   // rows staged per wave-round (8 output + 2 halo)

typedef float nf4 __attribute__((ext_vector_type(4)));
typedef __attribute__((address_space(1))) const unsigned int glo_u32;
typedef __attribute__((address_space(3))) unsigned int lds_u32;

// Persistent-slice, wave-private DOUBLE-BUFFERED pipeline (no __syncthreads):
//   block = 1 slice (128 rows) = 4 rounds x 32 rows; wave w owns rows
//   32r + 8w .. +7 each round, staged in its own 2-deep LDS buffer.
//   Round r body: issue masks(r+1) -> regs, issue DMA(r+1) -> buf[(r+1)&1],
//   pack masks(r) -> LDS, counted s_waitcnt vmcnt(N) (keeps next-round loads
//   in flight), compute(r) from buf[r&1].
//   VMEM counts per region: A(mask)=10, B(gload_lds)=5, S(stores)=4
//   => N after last gl(r): r0: A1+B1=15; r1/r2: S+A+B=19; r3: S=4.
//   "" memory asm after each DMA batch pins batch boundaries (strays can only
//   make the wait stricter, never looser).
__global__ __launch_bounds__(256, 3)
void brown_kernel(const float* __restrict__ inp,
                  const int*  __restrict__ dirp,
                  const int*  __restrict__ prb,
                  float* __restrict__ out)
{
    __shared__ __align__(16) float s_in[8 * LROWS * W];   // 4 waves x 2 bufs = 40960 B
    __shared__ unsigned int        s_mk[8 * LROWS * 32];  //                  = 10240 B

    const int tid  = threadIdx.x;
    const int wid  = tid >> 6;           // wave 0..3
    const int lane = tid & 63;
    const size_t base = (size_t)blockIdx.x * (size_t)(H * W);

    float*        sb0 = s_in + (wid * 2 + 0) * (LROWS * W);
    float*        sb1 = s_in + (wid * 2 + 1) * (LROWS * W);
    unsigned int* sm0 = s_mk + (wid * 2 + 0) * (LROWS * 32);
    unsigned int* sm1 = s_mk + (wid * 2 + 1) * (LROWS * 32);

    // ---- staging helpers (10 rows x 32 words = 5 exact wave-iters) ----
    auto issue_masks = [&](int r, int4 (&dv)[5], int4 (&pv)[5]) {
        const int wr0 = (r << 5) + (wid << 3);
        #pragma unroll
        for (int w = 0; w < 5; ++w) {
            const int idx = w * 64 + lane;
            const int Lr  = idx >> 5;
            const int c4  = idx & 31;
            const int gr  = wr0 - 1 + Lr;
            if ((unsigned)gr < (unsigned)H) {
                dv[w] = ((const int4*)(dirp + base + (size_t)gr * W))[c4];
                pv[w] = ((const int4*)(prb  + base + (size_t)gr * W))[c4];
            } else {
                dv[w] = make_int4(8, 8, 8, 8);
                pv[w] = make_int4(100, 100, 100, 100);  // > P_THRESH -> inactive
            }
        }
    };
    auto issue_dma = [&](int r, float* sb) {
        const int wr0 = (r << 5) + (wid << 3);
        #pragma unroll
        for (int w = 0; w < 5; ++w) {
            const int idx = w * 64 + lane;
            const int Lr  = idx >> 5;
            const int c4  = idx & 31;
            const int gr  = wr0 - 1 + Lr;
            const int gri = (gr < 0) ? 1 : ((gr >= H) ? (H - 2) : gr);  // reflect row
            const float* gp = inp + base + (size_t)gri * W + c4 * 4;
            __builtin_amdgcn_global_load_lds((glo_u32*)gp, (lds_u32*)(sb + idx * 4), 16, 0, 0);
        }
        asm volatile("" ::: "memory");   // pin batch boundary for vmcnt counting
    };
    // mask byte: 0..7 = direction if prob<=20, 8 = inactive
    auto pack_masks = [&](int4 (&dv)[5], int4 (&pv)[5], unsigned int* smk) {
        #pragma unroll
        for (int w = 0; w < 5; ++w) {
            const int idx = w * 64 + lane;
            const unsigned a  = (pv[w].x <= P_THRESH) ? (unsigned)dv[w].x : 8u;
            const unsigned b  = (pv[w].y <= P_THRESH) ? (unsigned)dv[w].y : 8u;
            const unsigned cc = (pv[w].z <= P_THRESH) ? (unsigned)dv[w].z : 8u;
            const unsigned d  = (pv[w].w <= P_THRESH) ? (unsigned)dv[w].w : 8u;
            smk[idx] = a | (b << 8) | (cc << 16) | (d << 24);
        }
    };

    // ---- compute geometry: lanes 0-31 rows 0-3, lanes 32-63 rows 4-7; 4 cols ----
    const int cq   = lane & 31;
    const int rh   = lane >> 5;
    const int j0   = cq << 2;
    const int lrb  = rh << 2;
    const int cqm1 = (cq > 0)  ? cq - 1 : 0;
    const int cqp1 = (cq < 31) ? cq + 1 : 31;

    auto compute = [&](int r, const float* sb, const unsigned int* smk) {
        const int wr0 = (r << 5) + (wid << 3);

        auto load_row = [&](int L, float v[6], unsigned& ma, unsigned& mb) {
            const float4   c   = ((const float4*)(sb + L * W))[cq];
            const unsigned mwc = smk[L * 32 + cq];
            const unsigned mwl = smk[L * 32 + cqm1];
            const unsigned mwr = smk[L * 32 + cqp1];
            const float lf = __shfl_up(c.w, 1);    // lane cq-1: col j0-1
            const float rt = __shfl_down(c.x, 1);  // lane cq+1: col j0+4
            v[1] = c.x; v[2] = c.y; v[3] = c.z; v[4] = c.w;
            v[0] = (cq > 0)  ? lf : c.y;   // reflect col -1 -> col 1
            v[5] = (cq < 31) ? rt : c.z;   // reflect col 128 -> col 126
            const unsigned ml = (cq > 0)  ? (mwl >> 24)  : 8u;
            const unsigned mr = (cq < 31) ? (mwr & 255u) : 8u;
            ma = (mwc << 8) | ml;
            mb = (mwc >> 8) | (mr << 24);
        };

        float va[6], vb[6], vc[6];
        unsigned maa, mab, mba, mbb, mca, mcb;
        load_row(lrb + 0, va, maa, mab);
        load_row(lrb + 1, vb, mba, mbb);

        #pragma unroll
        for (int rr = 0; rr < 4; ++rr) {
            load_row(lrb + rr + 2, vc, mca, mcb);

            const int gi = wr0 + lrb + rr;
            float cs[6];
            #pragma unroll
            for (int w = 0; w < 6; ++w) cs[w] = va[w] + vb[w] + vc[w];

            nf4 res;
            #pragma unroll
            for (int p = 0; p < 4; ++p) {
                const float avg = (cs[p] + cs[p + 1] + cs[p + 2]) * (1.0f / 9.0f);
                // packed window bytes: b0 = m[win p], b1 = m[p+1], b2 = m[p+2]
                const unsigned wTop = (p < 2) ? (maa >> (8 * p)) : (mab >> (8 * (p - 2)));
                const unsigned wMid = (p < 2) ? (mba >> (8 * p)) : (mbb >> (8 * (p - 2)));
                const unsigned wBot = (p < 2) ? (mca >> (8 * p)) : (mcb >> (8 * (p - 2)));

                float val = vb[p + 1];   // input[i][j]
                int dl = -1;             // direction of last A-write
                // A-writes ascending d; source offset = (-di,-dj)
                if (((wBot >> 16) & 255u) == 0u) { val = vc[p + 2]; dl = 0; }
                if (((wBot >>  8) & 255u) == 1u) { val = vc[p + 1]; dl = 1; }
                if (( wBot        & 255u) == 2u) { val = vc[p];     dl = 2; }
                if (((wMid >> 16) & 255u) == 3u) { val = vb[p + 2]; dl = 3; }
                if (( wMid        & 255u) == 5u) { val = vb[p];     dl = 5; }
                if (((wTop >> 16) & 255u) == 6u) { val = va[p + 2]; dl = 6; }
                if (((wTop >>  8) & 255u) == 7u) { val = va[p + 1]; dl = 7; }

                // B-write (avg) at own dir msel; wins iff valid and msel >= dl
                const int msel = (int)((wMid >> 8) & 255u);  // own mask = m[1][p+1]
                const int q3 = (msel * 11) >> 5;             // msel/3 for 0..8
                const int di = q3 - 1;
                const int dj = msel - q3 * 3 - 1;
                const int ti = gi + di;
                const int tj = j0 + p + dj;
                const bool bok = (msel < 8) & ((unsigned)ti < 128u) & ((unsigned)tj < 128u);
                if (bok & (msel >= dl)) val = avg;
                res[p] = val;
            }
            __builtin_nontemporal_store(res, (nf4*)(out + base + (size_t)gi * W) + cq);

            #pragma unroll
            for (int w = 0; w < 6; ++w) { va[w] = vb[w]; vb[w] = vc[w]; }
            maa = mba; mab = mbb; mba = mca; mbb = mcb;
        }
    };

    // ---- pipeline: 4 rounds, 2-deep ----
    int4 dv0[5], pv0[5], dv1[5], pv1[5];

    issue_masks(0, dv0, pv0);
    issue_dma(0, sb0);

    // round 0
    issue_masks(1, dv1, pv1);
    issue_dma(1, sb1);
    pack_masks(dv0, pv0, sm0);
    asm volatile("s_waitcnt vmcnt(15)" ::: "memory");   // gl(0) done; mk(1)+gl(1) in flight
    compute(0, sb0, sm0);

    // round 1
    issue_masks(2, dv0, pv0);
    issue_dma(2, sb0);
    pack_masks(dv1, pv1, sm1);
    asm volatile("s_waitcnt vmcnt(19)" ::: "memory");   // gl(1) done; S0+mk(2)+gl(2) in flight
    compute(1, sb1, sm1);

    // round 2
    issue_masks(3, dv1, pv1);
    issue_dma(3, sb1);
    pack_masks(dv0, pv0, sm0);
    asm volatile("s_waitcnt vmcnt(19)" ::: "memory");   // gl(2) done; S1+mk(3)+gl(3) in flight
    compute(2, sb0, sm0);

    // round 3 (no prefetch)
    pack_masks(dv1, pv1, sm1);
    asm volatile("s_waitcnt vmcnt(4)" ::: "memory");    // gl(3) done; S2 may remain
    compute(3, sb1, sm1);
}

extern "C" void kernel_launch(void* const* d_in, const int* in_sizes, int n_in,
                              void* d_out, int out_size, void* d_ws, size_t ws_size,
                              hipStream_t stream) {
    const float* inp  = (const float*)d_in[0];
    const int*   dirp = (const int*)d_in[1];
    const int*   prb  = (const int*)d_in[2];
    float* out = (float*)d_out;

    const int slices = in_sizes[0] / (H * W);   // 2048
    brown_kernel<<<slices, 256, 0, stream>>>(inp, dirp, prb, out);
}

// Round 7
// 413.968 us; speedup vs baseline: 1.0048x; 1.0048x over previous
//
#include <hip/hip_runtime.h>
#include <cstddef>

#define H 128
#define W 128
#define P_THRESH 20

typedef float nf2 __attribute__((ext_vector_type(2)));
typedef __attribute__((address_space(1))) const unsigned int glo_u32;
typedef __attribute__((address_space(3))) unsigned int lds_u32;

// Persistent-slice, wave-private double-buffered pipeline, minimal LDS:
//   block = 128 thr = 2 waves; block owns 1 slice; 8 rounds x 16 rows
//   (wave w: rows r*16 + w*8 .. +7). Input staged via global_load_lds into a
//   2-deep wave-private buffer (10 rows incl. halo). Masks NEVER touch LDS:
//   packed into 5 VGPR words/lane (stage layout), redistributed by __shfl at
//   compute (pure lane permutation). Lane = 2 cols x all rows -> all mask reg
//   indices compile-time. Border-OOB writes folded into the mask at pack time
//   (provably equivalent to inactive), so the per-px B-check is 2 compares.
//   vmcnt(13) = 8 stores + 5 next-DMA newer than current tile's DMA; never 0.
__global__ __launch_bounds__(128, 4)
void brown_kernel(const float* __restrict__ inp,
                  const int*  __restrict__ dirp,
                  const int*  __restrict__ prb,
                  float* __restrict__ out)
{
    __shared__ __align__(16) float s_in[2 * 2 * 10 * W];   // 20480 B -> 8 blocks/CU

    const int tid  = threadIdx.x;
    const int wid  = tid >> 6;           // wave 0..1
    const int lane = tid & 63;
    const size_t base = (size_t)blockIdx.x * (size_t)(H * W);

    float* sb0 = s_in + (wid * 2 + 0) * (10 * W);
    float* sb1 = s_in + (wid * 2 + 1) * (10 * W);

    const int hl  = lane >> 5;           // stage row parity (rows 2k+hl)
    const int cg  = lane & 31;           // stage col group (4 cols)
    const int cgc = lane >> 1;           // compute col word for this lane
    // neighbor word for the halo byte (even lane needs left, odd needs right)
    const int cgn = (lane & 1) ? ((cgc < 31) ? cgc + 1 : 31)
                               : ((cgc > 0) ? cgc - 1 : 0);

    int4 dv[5], pv[5];   // single mask bank, reused every round

    // mask loads for the round whose first output row is wr0 (10 rows coop)
    auto issue_mk = [&](int wr0) {
        #pragma unroll
        for (int k = 0; k < 5; ++k) {
            const int gr = wr0 - 1 + 2 * k + hl;
            if ((unsigned)gr < (unsigned)H) {
                dv[k] = ((const int4*)(dirp + base + (size_t)gr * W))[cg];
                pv[k] = ((const int4*)(prb  + base + (size_t)gr * W))[cg];
            } else {
                dv[k] = make_int4(8, 8, 8, 8);
                pv[k] = make_int4(100, 100, 100, 100);   // > P_THRESH -> inactive
            }
        }
    };
    // input DMA: 10 rows x 32 float4 = 5 exact wave-iterations, reflect rows
    auto issue_gl = [&](int wr0, float* sb) {
        #pragma unroll
        for (int k = 0; k < 5; ++k) {
            const int idx = k * 64 + lane;
            const int L   = idx >> 5;
            const int c4  = idx & 31;
            const int gr  = wr0 - 1 + L;
            const int gri = (gr < 0) ? 1 : ((gr >= H) ? (H - 2) : gr);
            const float* gp = inp + base + (size_t)gri * W + c4 * 4;
            __builtin_amdgcn_global_load_lds((glo_u32*)gp, (lds_u32*)(sb + idx * 4), 16, 0, 0);
        }
        asm volatile("" ::: "memory");   // pin DMA batch for vmcnt counting
    };
    // pack masks -> pk[5] words, folding target-OOB writes to inactive(8).
    // mask byte: 0..7 = direction if prob<=20 AND target in-image, else 8.
    auto pack = [&](int wr0, unsigned pk[5]) {
        #pragma unroll
        for (int k = 0; k < 5; ++k) {
            const unsigned a = (pv[k].x <= P_THRESH) ? (unsigned)dv[k].x : 8u;
            const unsigned b = (pv[k].y <= P_THRESH) ? (unsigned)dv[k].y : 8u;
            const unsigned c = (pv[k].z <= P_THRESH) ? (unsigned)dv[k].z : 8u;
            const unsigned d = (pv[k].w <= P_THRESH) ? (unsigned)dv[k].w : 8u;
            unsigned m = a | (b << 8) | (c << 16) | (d << 24);
            const int gr = wr0 - 1 + 2 * k + hl;
            if (gr == 0) {            // top row: d in {0,1,2} writes up -> OOB
                unsigned mm = 0;
                #pragma unroll
                for (int i2 = 0; i2 < 4; ++i2) {
                    unsigned bb = (m >> (8 * i2)) & 255u;
                    bb = (bb <= 2u) ? 8u : bb;
                    mm |= bb << (8 * i2);
                }
                m = mm;
            } else if (gr == H - 1) { // bottom row: d in {6,7} writes down -> OOB
                unsigned mm = 0;
                #pragma unroll
                for (int i2 = 0; i2 < 4; ++i2) {
                    unsigned bb = (m >> (8 * i2)) & 255u;
                    bb = (bb >= 6u) ? 8u : bb;
                    mm |= bb << (8 * i2);
                }
                m = mm;
            }
            if (cg == 0) {            // image col 0: d in {0,3,6} (dj=-1) -> OOB
                const unsigned b0 = m & 255u;
                if ((0x49u >> b0) & 1u) m = (m & ~255u) | 8u;
            }
            if (cg == 31) {           // image col 127: d in {2,5} (dj=+1) -> OOB
                const unsigned b3 = m >> 24;
                if ((0x24u >> b3) & 1u) m = (m & 0x00FFFFFFu) | (8u << 24);
            }
            pk[k] = m;
        }
    };

    auto round_compute = [&](int wr0, const float* sb, const unsigned pk[5]) {
        // redistribute masks: maRow[L] bytes = mask cols 2*lane-1 .. 2*lane+2
        unsigned maRow[10];
        #pragma unroll
        for (int L = 0; L < 10; ++L) {
            const int sb5 = (L & 1) << 5;
            const unsigned mwc = __shfl(pk[L >> 1], sb5 | cgc, 64);
            const unsigned nw  = __shfl(pk[L >> 1], sb5 | cgn, 64);
            const unsigned nb  = (lane == 0 || lane == 63) ? 8u
                               : ((lane & 1) ? (nw & 255u) : (nw >> 24));
            maRow[L] = (lane & 1) ? ((mwc >> 8) | (nb << 24))
                                  : ((mwc << 8) | nb);
        }
        // sliding 3-row input window (4 cols: j0-1 .. j0+2, j0 = 2*lane)
        float va[4], vb_[4], vc_[4];
        auto load_irow = [&](int L, float v[4]) {
            const nf2 c = *((const nf2*)(sb + L * W) + lane);
            const float lf = __shfl_up(c.y, 1);
            const float rt = __shfl_down(c.x, 1);
            v[1] = c.x; v[2] = c.y;
            v[0] = (lane == 0)  ? c.y : lf;   // reflect col -1 -> 1
            v[3] = (lane == 63) ? c.x : rt;   // reflect col 128 -> 126
        };
        load_irow(0, va);
        load_irow(1, vb_);
        #pragma unroll
        for (int rr = 0; rr < 8; ++rr) {
            load_irow(rr + 2, vc_);
            const int gi = wr0 + rr;
            float cs[4];
            #pragma unroll
            for (int w = 0; w < 4; ++w) cs[w] = va[w] + vb_[w] + vc_[w];
            const unsigned maT = maRow[rr], maM = maRow[rr + 1], maB = maRow[rr + 2];
            nf2 res;
            #pragma unroll
            for (int p = 0; p < 2; ++p) {
                const float avg = (cs[p] + cs[p + 1] + cs[p + 2]) * (1.0f / 9.0f);
                const unsigned wT = maT >> (8 * p);
                const unsigned wM = maM >> (8 * p);
                const unsigned wB = maB >> (8 * p);
                float val = vb_[p + 1];   // input[i][j]
                int dl = -1;              // direction of last A-write
                if (((wB >> 16) & 255u) == 0u) { val = vc_[p + 2]; dl = 0; }
                if (((wB >>  8) & 255u) == 1u) { val = vc_[p + 1]; dl = 1; }
                if (( wB        & 255u) == 2u) { val = vc_[p];     dl = 2; }
                if (((wM >> 16) & 255u) == 3u) { val = vb_[p + 2]; dl = 3; }
                if (( wM        & 255u) == 5u) { val = vb_[p];     dl = 5; }
                if (((wT >> 16) & 255u) == 6u) { val = va[p + 2];  dl = 6; }
                if (((wT >>  8) & 255u) == 7u) { val = va[p + 1];  dl = 7; }
                // B-write: borders pre-folded, so just priority + active
                const int msel = (int)((wM >> 8) & 255u);
                if ((msel < 8) & (msel >= dl)) val = avg;
                res[p] = val;
            }
            __builtin_nontemporal_store(res, (nf2*)(out + base + (size_t)gi * W) + lane);
            #pragma unroll
            for (int w = 0; w < 4; ++w) { va[w] = vb_[w]; vb_[w] = vc_[w]; }
        }
    };

    // ---- pipeline: 8 rounds, 2-deep, wave-private, no __syncthreads ----
    issue_gl(wid * 8, sb0);
    issue_mk(wid * 8);
    float* scur = sb0;
    float* snxt = sb1;
    for (int r = 0; r < 7; ++r) {
        const int wr0 = r * 16 + wid * 8;
        issue_gl(wr0 + 16, snxt);           // next-tile DMA into other buffer
        unsigned pk[5];
        pack(wr0, pk);                       // auto-waits this round's mask regs
        // gl(r) done: ops newer than it = st(r-1)<=8 + gl(r+1)=5 -> 13
        asm volatile("s_waitcnt vmcnt(13)" ::: "memory");
        __builtin_amdgcn_sched_barrier(0);
        issue_mk(wr0 + 16);                  // next-round masks (reg bank reuse)
        __builtin_amdgcn_sched_barrier(0);
        round_compute(wr0, scur, pk);
        float* t = scur; scur = snxt; snxt = t;
    }
    {
        const int wr0 = 7 * 16 + wid * 8;
        unsigned pk[5];
        pack(wr0, pk);
        asm volatile("s_waitcnt vmcnt(8)" ::: "memory");   // st(6) only newer
        round_compute(wr0, scur, pk);
    }
}

extern "C" void kernel_launch(void* const* d_in, const int* in_sizes, int n_in,
                              void* d_out, int out_size, void* d_ws, size_t ws_size,
                              hipStream_t stream) {
    const float* inp  = (const float*)d_in[0];
    const int*   dirp = (const int*)d_in[1];
    const int*   prb  = (const int*)d_in[2];
    float* out = (float*)d_out;

    const int slices = in_sizes[0] / (H * W);   // 2048
    brown_kernel<<<slices, 128, 0, stream>>>(inp, dirp, prb, out);
}

// Round 8
// 397.229 us; speedup vs baseline: 1.0472x; 1.0421x over previous
//
#include <hip/hip_runtime.h>
#include <cstddef>

#define H 128
#define W 128
#define P_THRESH 20

typedef float f4u __attribute__((ext_vector_type(4), aligned(4)));  // 4B-aligned vec loads
typedef int   i4u __attribute__((ext_vector_type(4), aligned(4)));
typedef float nf2 __attribute__((ext_vector_type(2)));

// Pure-streaming, zero-LDS, zero-shuffle, zero-sync kernel.
//   thread = 1 row x 2 cols. Nine independent 16B unaligned loads supply the
//   full 3x4 window (cols j0-1..j0+2): the column halo comes from the load
//   window, NOT from a shuffle network -> the only intra-thread latency is one
//   parallel load batch, hidden by occupancy (no LDS/VGPR pressure: ~8 w/SIMD).
//   Row halo: wave-uniform clamped row index (input reflects; masks folded).
//   Border writes folded into mask bytes at pack time (r7-verified):
//   byte = dir if prob<=20 AND target px in-image, else 8 (inactive).
__global__ __launch_bounds__(256, 6)
void brown_kernel(const float* __restrict__ inp,
                  const int*  __restrict__ dirp,
                  const int*  __restrict__ prb,
                  float* __restrict__ out)
{
    const int tid  = threadIdx.x;
    const int lane = tid & 63;
    const int bid  = blockIdx.x;
    const int slice = bid >> 5;
    const int gi   = ((bid & 31) << 2) | (tid >> 6);   // row 0..127 (wave-uniform)
    const size_t base = (size_t)slice * (size_t)(H * W);

    const int j0 = lane << 1;                           // own cols j0, j0+1
    // load window start col: j0-1 clamped to [0, W-4] (edge lanes fixed up below)
    const int cl = (lane == 0) ? 0 : ((lane == 63) ? (W - 4) : (j0 - 1));

    const int rT = (gi == 0) ? 1 : gi - 1;              // reflect row for input
    const int rB = (gi == H - 1) ? H - 2 : gi + 1;

    const float* ip = inp  + base;
    const int*   dp = dirp + base;
    const int*   pp = prb  + base;

    // ---- 9 independent loads, issued back-to-back ----
    const f4u iT = *(const f4u*)(ip + (size_t)rT * W + cl);
    const f4u iM = *(const f4u*)(ip + (size_t)gi * W + cl);
    const f4u iB = *(const f4u*)(ip + (size_t)rB * W + cl);
    const i4u dT = *(const i4u*)(dp + (size_t)rT * W + cl);
    const i4u dM = *(const i4u*)(dp + (size_t)gi * W + cl);
    const i4u dB = *(const i4u*)(dp + (size_t)rB * W + cl);
    const i4u pT = *(const i4u*)(pp + (size_t)rT * W + cl);
    const i4u pM = *(const i4u*)(pp + (size_t)gi * W + cl);
    const i4u pB = *(const i4u*)(pp + (size_t)rB * W + cl);

    auto packm = [](i4u d, i4u p) -> unsigned {
        const unsigned a = (p.x <= P_THRESH) ? (unsigned)d.x : 8u;
        const unsigned b = (p.y <= P_THRESH) ? (unsigned)d.y : 8u;
        const unsigned c = (p.z <= P_THRESH) ? (unsigned)d.z : 8u;
        const unsigned e = (p.w <= P_THRESH) ? (unsigned)d.w : 8u;
        return a | (b << 8) | (c << 16) | (e << 24);
    };
    unsigned mT = packm(dT, pT);
    unsigned mM = packm(dM, pM);
    unsigned mB = packm(dB, pB);

    // ---- row-border folds (wave-uniform branches, 2 waves/slice) ----
    if (gi == 0) {
        mT = 0x08080808u;                 // no row above: never a source
        unsigned r = 0;                   // own row: d in {0,1,2} writes up -> OOB
        #pragma unroll
        for (int i2 = 0; i2 < 4; ++i2) {
            unsigned b = (mM >> (8 * i2)) & 255u;
            b = (b <= 2u) ? 8u : b;
            r |= b << (8 * i2);
        }
        mM = r;
    } else if (gi == H - 1) {
        mB = 0x08080808u;
        unsigned r = 0;                   // d in {6,7} writes down -> OOB
        #pragma unroll
        for (int i2 = 0; i2 < 4; ++i2) {
            unsigned b = (mM >> (8 * i2)) & 255u;
            b = (b >= 6u) ? 8u : b;
            r |= b << (8 * i2);
        }
        mM = r;
    }

    // ---- edge-lane fixup (2 of 64 lanes; short divergent blocks) ----
    // window layout goal: bytes/floats = cols {j0-1, j0, j0+1, j0+2}
    float vT[4] = {iT.x, iT.y, iT.z, iT.w};
    float vM[4] = {iM.x, iM.y, iM.z, iM.w};
    float vB[4] = {iB.x, iB.y, iB.z, iB.w};
    if (lane == 0) {           // loaded cols {0,1,2,3}; want {ref(-1)=1,0,1,2}
        vT[0] = iT.y; vT[1] = iT.x; vT[2] = iT.y; vT[3] = iT.z;
        vM[0] = iM.y; vM[1] = iM.x; vM[2] = iM.y; vM[3] = iM.z;
        vB[0] = iB.y; vB[1] = iB.x; vB[2] = iB.y; vB[3] = iB.z;
        mT = (mT << 8) | 8u;
        mB = (mB << 8) | 8u;
        mM = (mM << 8) | 8u;
        const unsigned b1 = (mM >> 8) & 255u;        // col 0: d in {0,3,6} -> OOB
        if ((0x49u >> b1) & 1u) mM = (mM & ~0xFF00u) | (8u << 8);
    } else if (lane == 63) {   // loaded cols {124..127}; want {125,126,127,ref(128)=126}
        vT[0] = iT.y; vT[1] = iT.z; vT[2] = iT.w; vT[3] = iT.z;
        vM[0] = iM.y; vM[1] = iM.z; vM[2] = iM.w; vM[3] = iM.z;
        vB[0] = iB.y; vB[1] = iB.z; vB[2] = iB.w; vB[3] = iB.z;
        mT = (mT >> 8) | 0x08000000u;
        mB = (mB >> 8) | 0x08000000u;
        mM = (mM >> 8) | 0x08000000u;
        const unsigned b2 = (mM >> 16) & 255u;       // col 127: d in {2,5} -> OOB
        if ((0x24u >> b2) & 1u) mM = (mM & ~0xFF0000u) | (8u << 16);
    }

    // ---- compute 2 px ----
    float cs[4];
    #pragma unroll
    for (int w = 0; w < 4; ++w) cs[w] = vT[w] + vM[w] + vB[w];

    nf2 res;
    #pragma unroll
    for (int p = 0; p < 2; ++p) {
        const float avg = (cs[p] + cs[p + 1] + cs[p + 2]) * (1.0f / 9.0f);
        const unsigned wT = mT >> (8 * p);   // b0=m[p] b1=m[p+1] b2=m[p+2]
        const unsigned wM = mM >> (8 * p);
        const unsigned wB = mB >> (8 * p);

        float val = vM[p + 1];   // input[i][j]
        int dl = -1;             // direction of last A-write
        // A-writes ascending d; source offset = (-di,-dj)
        if (((wB >> 16) & 255u) == 0u) { val = vB[p + 2]; dl = 0; }
        if (((wB >>  8) & 255u) == 1u) { val = vB[p + 1]; dl = 1; }
        if (( wB        & 255u) == 2u) { val = vB[p];     dl = 2; }
        if (((wM >> 16) & 255u) == 3u) { val = vM[p + 2]; dl = 3; }
        if (( wM        & 255u) == 5u) { val = vM[p];     dl = 5; }
        if (((wT >> 16) & 255u) == 6u) { val = vT[p + 2]; dl = 6; }
        if (((wT >>  8) & 255u) == 7u) { val = vT[p + 1]; dl = 7; }

        // B-write (avg): borders pre-folded -> just active + priority
        const int msel = (int)((wM >> 8) & 255u);
        if ((msel < 8) & (msel >= dl)) val = avg;
        res[p] = val;
    }
    // plain coalesced store (nt removed: it inflated WRITE_SIZE in r6/r7)
    *(nf2*)(out + base + (size_t)gi * W + j0) = res;
}

extern "C" void kernel_launch(void* const* d_in, const int* in_sizes, int n_in,
                              void* d_out, int out_size, void* d_ws, size_t ws_size,
                              hipStream_t stream) {
    const float* inp  = (const float*)d_in[0];
    const int*   dirp = (const int*)d_in[1];
    const int*   prb  = (const int*)d_in[2];
    float* out = (float*)d_out;

    const int slices = in_sizes[0] / (H * W);   // 2048
    const int grid = slices * 32;               // 4 rows per block -> 65536
    brown_kernel<<<grid, 256, 0, stream>>>(inp, dirp, prb, out);
}

// Round 9
// 379.595 us; speedup vs baseline: 1.0958x; 1.0465x over previous
//
#include <hip/hip_runtime.h>
#include <cstddef>

#define H 128
#define W 128
#define P_THRESH 20

typedef float f4u __attribute__((ext_vector_type(4), aligned(4)));
typedef int   i4u __attribute__((ext_vector_type(4), aligned(4)));
typedef float nf2 __attribute__((ext_vector_type(2)));

// r8 streaming shape + de-duplicated masks in tiny LDS.
//   block = 4 rows x 128 cols (256 thr, 2 px/thread, wave = one row).
//   Masks: 6 rows (r0-1..r0+4) packed ONCE per block into LDS bytes
//   (was 3x redundant per-thread packing in r8). Borders folded at pack:
//   byte = dir if prob<=20 AND target px in-image, else 8.
//   Guard word + per-row 4B pad (all 8s) => compute-side mask window read
//   is edge-case-free: 2 LDS words + funnel shift (sh in {8,24}, never 0).
//   Input: r8's 3 unaligned f4u global loads (L1 absorbs 3x row overlap),
//   issued BEFORE the barrier so they fly during it; edge fixup via 6
//   cndmask/row instead of divergent branches.
__global__ __launch_bounds__(256, 8)
void brown_kernel(const float* __restrict__ inp,
                  const int*  __restrict__ dirp,
                  const int*  __restrict__ prb,
                  float* __restrict__ out)
{
    // [0] = guard word; then 6 rows x 33 words (128 cols + 4B pad, all 8s)
    __shared__ unsigned int s_mk[1 + 6 * 33];   // 796 B -> LDS never caps occupancy

    const int tid   = threadIdx.x;
    const int bid   = blockIdx.x;
    const int slice = bid >> 5;
    const int r0    = (bid & 31) << 2;
    const size_t base = (size_t)slice * (size_t)(H * W);

    const int lane = tid & 63;
    const int row  = tid >> 6;          // 0..3 (wave-uniform)
    const int gi   = r0 + row;
    const int j0   = lane << 1;

    // ---- input loads first: independent of LDS, in flight across the barrier ----
    const int cl = (lane == 0) ? 0 : ((lane == 63) ? (W - 4) : (j0 - 1));
    const int rT = (gi == 0) ? 1 : gi - 1;          // reflect rows for avg
    const int rB = (gi == H - 1) ? H - 2 : gi + 1;
    const float* ip = inp + base;
    const f4u iT = *(const f4u*)(ip + (size_t)rT * W + cl);
    const f4u iM = *(const f4u*)(ip + (size_t)gi * W + cl);
    const f4u iB = *(const f4u*)(ip + (size_t)rB * W + cl);

    // ---- pack phase: 6 mask rows, once per block, borders folded ----
    if (tid < 192) {
        const int r6 = tid >> 5;        // LDS mask row 0..5
        const int w  = tid & 31;        // word = 4 cols
        const int gr = r0 + r6 - 1;     // image row
        unsigned m;
        if ((unsigned)gr < (unsigned)H) {
            const i4u dv = *(const i4u*)(dirp + base + (size_t)gr * W + 4 * w);
            const i4u pv = *(const i4u*)(prb  + base + (size_t)gr * W + 4 * w);
            const unsigned a = (pv.x <= P_THRESH) ? (unsigned)dv.x : 8u;
            const unsigned b = (pv.y <= P_THRESH) ? (unsigned)dv.y : 8u;
            const unsigned c = (pv.z <= P_THRESH) ? (unsigned)dv.z : 8u;
            const unsigned e = (pv.w <= P_THRESH) ? (unsigned)dv.w : 8u;
            m = a | (b << 8) | (c << 16) | (e << 24);
            if (gr == 0) {              // top row: d in {0,1,2} writes up -> OOB
                unsigned mm = 0;
                #pragma unroll
                for (int i2 = 0; i2 < 4; ++i2) {
                    unsigned bb = (m >> (8 * i2)) & 255u;
                    bb = (bb <= 2u) ? 8u : bb;
                    mm |= bb << (8 * i2);
                }
                m = mm;
            } else if (gr == H - 1) {   // bottom row: d in {6,7} writes down -> OOB
                unsigned mm = 0;
                #pragma unroll
                for (int i2 = 0; i2 < 4; ++i2) {
                    unsigned bb = (m >> (8 * i2)) & 255u;
                    bb = (bb >= 6u) ? 8u : bb;
                    mm |= bb << (8 * i2);
                }
                m = mm;
            }
            if (w == 0) {               // image col 0: d in {0,3,6} (dj=-1) -> OOB
                const unsigned b0 = m & 255u;
                if ((0x49u >> b0) & 1u) m = (m & ~255u) | 8u;
            }
            if (w == 31) {              // image col 127: d in {2,5} (dj=+1) -> OOB
                const unsigned b3 = m >> 24;
                if ((0x24u >> b3) & 1u) m = (m & 0x00FFFFFFu) | (8u << 24);
            }
        } else {
            m = 0x08080808u;            // out-of-image rows never source writes
        }
        s_mk[1 + 33 * r6 + w] = m;
        if (w == 31) s_mk[1 + 33 * r6 + 32] = 0x08080808u;   // row pad
    } else if (tid == 192) {
        s_mk[0] = 0x08080808u;          // guard before row 0
    }
    __syncthreads();

    // ---- mask windows: bytes = cols {j0-1, j0, j0+1, j0+2}; no edge cases ----
    // byte addr of col j0-1 in row rm (incl. 4B guard) = 4 + 132*rm + j0 - 1
    unsigned mrow[3];
    #pragma unroll
    for (int dr = 0; dr < 3; ++dr) {
        const int addr = 132 * (row + dr) + (j0 + 3);
        const unsigned w0 = s_mk[addr >> 2];
        const unsigned w1 = s_mk[(addr >> 2) + 1];
        const int sh = 8 * (addr & 3);           // lane even: 24, odd: 8 (never 0)
        mrow[dr] = (w0 >> sh) | (w1 << (32 - sh));
    }
    const unsigned mT = mrow[0], mM = mrow[1], mB = mrow[2];

    // ---- float windows: cols {j0-1, j0, j0+1, j0+2}; 6 cndmask/row edge fix ----
    const bool e0 = (lane == 0), e63 = (lane == 63), eE = e0 | e63;
    float vT[4], vM[4], vB[4];
    {
        // lane 0 loaded cols {0..3}, wants {1,0,1,2}; lane 63 loaded {124..127},
        // wants {125,126,127,126}; others loaded exactly {j0-1..j0+2}.
        vT[0] = eE ? iT.y : iT.x;  vT[1] = e0 ? iT.x : (e63 ? iT.z : iT.y);
        vT[2] = e0 ? iT.y : (e63 ? iT.w : iT.z);  vT[3] = eE ? iT.z : iT.w;
        vM[0] = eE ? iM.y : iM.x;  vM[1] = e0 ? iM.x : (e63 ? iM.z : iM.y);
        vM[2] = e0 ? iM.y : (e63 ? iM.w : iM.z);  vM[3] = eE ? iM.z : iM.w;
        vB[0] = eE ? iB.y : iB.x;  vB[1] = e0 ? iB.x : (e63 ? iB.z : iB.y);
        vB[2] = e0 ? iB.y : (e63 ? iB.w : iB.z);  vB[3] = eE ? iB.z : iB.w;
    }

    // ---- compute 2 px ----
    float cs[4];
    #pragma unroll
    for (int w = 0; w < 4; ++w) cs[w] = vT[w] + vM[w] + vB[w];

    nf2 res;
    #pragma unroll
    for (int p = 0; p < 2; ++p) {
        const float avg = (cs[p] + cs[p + 1] + cs[p + 2]) * (1.0f / 9.0f);
        const unsigned wT = mT >> (8 * p);   // b0=m[p] b1=m[p+1] b2=m[p+2]
        const unsigned wM = mM >> (8 * p);
        const unsigned wB = mB >> (8 * p);

        float val = vM[p + 1];   // input[i][j]
        int dl = -1;             // direction of last A-write
        // A-writes ascending d; source offset = (-di,-dj)
        if (((wB >> 16) & 255u) == 0u) { val = vB[p + 2]; dl = 0; }
        if (((wB >>  8) & 255u) == 1u) { val = vB[p + 1]; dl = 1; }
        if (( wB        & 255u) == 2u) { val = vB[p];     dl = 2; }
        if (((wM >> 16) & 255u) == 3u) { val = vM[p + 2]; dl = 3; }
        if (( wM        & 255u) == 5u) { val = vM[p];     dl = 5; }
        if (((wT >> 16) & 255u) == 6u) { val = vT[p + 2]; dl = 6; }
        if (((wT >>  8) & 255u) == 7u) { val = vT[p + 1]; dl = 7; }

        // B-write (avg): borders pre-folded -> just active + priority
        const int msel = (int)((wM >> 8) & 255u);
        if ((msel < 8) & (msel >= dl)) val = avg;
        res[p] = val;
    }
    *(nf2*)(out + base + (size_t)gi * W + j0) = res;
}

extern "C" void kernel_launch(void* const* d_in, const int* in_sizes, int n_in,
                              void* d_out, int out_size, void* d_ws, size_t ws_size,
                              hipStream_t stream) {
    const float* inp  = (const float*)d_in[0];
    const int*   dirp = (const int*)d_in[1];
    const int*   prb  = (const int*)d_in[2];
    float* out = (float*)d_out;

    const int slices = in_sizes[0] / (H * W);   // 2048
    const int grid = slices * 32;               // 4 rows per block -> 65536
    brown_kernel<<<grid, 256, 0, stream>>>(inp, dirp, prb, out);
}